// Round 14
// baseline (56.032 us; speedup 1.0000x reference)
//
#include <hip/hip_runtime.h>
#include <hip/hip_bf16.h>
#include <stdint.h>

#define BATCH 16384
#define NCLS 1000
#define NPAD 1024        // 4 N-blocks x 256
#define EMB 768
#define KT 12            // K-steps of 64
#define BM 128
#define BN 256
#define ABYTES 8192      // 128 rows x 64 B
#define BUFB 24576       // A 8K + B 16K
#define GEMM_BLKS 512    // 128 mb x 4 nb, 2 blocks/CU

#define PREP_BATCH_BLKS 512   // 32 batch rows each
#define PREP_CENT_BLKS  32    // 32 centroid rows each (1024 padded)
#define PG 8                  // groups per block (4 rows each)
#define EMB_B 3072            // emb row bytes
#define LOG_B 4096            // logits row LDS stride (4000 valid)
#define PBUF (4 * EMB_B + 4 * LOG_B)   // 28672 per buffer

typedef __attribute__((ext_vector_type(4))) float f32x4;
typedef long v2i64 __attribute__((ext_vector_type(2)));

#define GLOAD16(g, l) __builtin_amdgcn_global_load_lds(              \
    (const __attribute__((address_space(1))) unsigned int*)(g),       \
    (__attribute__((address_space(3))) unsigned int*)(l), 16, 0, 0)

__device__ __forceinline__ float d4(float4 v) {
    return v.x*v.x + v.y*v.y + v.z*v.z + v.w*v.w;
}
__device__ __forceinline__ float e4(float4 v) {
    return __expf(v.x) + __expf(v.y) + __expf(v.z) + __expf(v.w);
}
__device__ __forceinline__ unsigned int pk8(float4 v, float s) {
    int p = 0;
    p = __builtin_amdgcn_cvt_pk_fp8_f32(v.x * s, v.y * s, p, false);
    p = __builtin_amdgcn_cvt_pk_fp8_f32(v.z * s, v.w * s, p, true);
    return (unsigned int)p;
}

// ---- prep via global_load_lds DMA pipeline (r13 lesson: regalloc will
// never keep reduce-kernel loads in flight; the DMA queue will).
// Blocks 0..511: 32 batch rows each (emb-norm + CE). Blocks 512..543:
// 32 centroid rows each (1024 padded, pads written as zero-scale).
// Per group of 4 rows: wave w stages+processes row w; dbuf LDS; 1 barrier
// per group; all reduces intra-wave. ----
__global__ __launch_bounds__(256) void prep_row(
    const float* __restrict__ emb, const float* __restrict__ cent,
    const float* __restrict__ logits, const int* __restrict__ targets,
    unsigned int* __restrict__ en8, unsigned int* __restrict__ cn8,
    float* __restrict__ ce_row)
{
    __shared__ __align__(128) uint8_t lds[2][PBUF];
    const int b    = blockIdx.x;
    const int tid  = threadIdx.x;
    const int w    = tid >> 6;
    const int lane = tid & 63;
    const bool isCent = b >= PREP_BATCH_BLKS;
    const int rbase = isCent ? (b - PREP_BATCH_BLKS) * 32 : b * 32;

#define PSTAGE(bf, g) do {                                                    \
    const int row_ = rbase + (g) * 4 + w;                                     \
    if (!isCent) {                                                            \
        const uint8_t* es_ = (const uint8_t*)(emb + (size_t)row_ * EMB);      \
        const uint8_t* ls_ = (const uint8_t*)(logits + (size_t)row_ * NCLS);  \
        _Pragma("unroll") for (int j = 0; j < 3; ++j)                         \
            GLOAD16(es_ + (lane + j * 64) * 16,                               \
                    &lds[bf][w * EMB_B + j * 1024 + lane * 16]);              \
        _Pragma("unroll") for (int j = 0; j < 3; ++j)                         \
            GLOAD16(ls_ + (lane + j * 64) * 16,                               \
                    &lds[bf][4 * EMB_B + w * LOG_B + j * 1024 + lane * 16]);  \
        if (lane < 58)                                                        \
            GLOAD16(ls_ + (lane + 192) * 16,                                  \
                    &lds[bf][4 * EMB_B + w * LOG_B + 3072 + lane * 16]);      \
    } else {                                                                  \
        const int cr_ = (row_ < NCLS) ? row_ : NCLS - 1;                      \
        const uint8_t* es_ = (const uint8_t*)(cent + (size_t)cr_ * EMB);      \
        _Pragma("unroll") for (int j = 0; j < 3; ++j)                         \
            GLOAD16(es_ + (lane + j * 64) * 16,                               \
                    &lds[bf][w * EMB_B + j * 1024 + lane * 16]);              \
    }                                                                         \
} while (0)

    int buf = 0;
    PSTAGE(0, 0);
    __syncthreads();

    for (int g = 0; g < PG; ++g) {
        if (g + 1 < PG) PSTAGE(buf ^ 1, g + 1);

        const int row = rbase + g * 4 + w;
        const uint8_t* eb = &lds[buf][w * EMB_B];
        float4 e0 = *(const float4*)(eb + lane * 16);
        float4 e1 = *(const float4*)(eb + 1024 + lane * 16);
        float4 e2 = *(const float4*)(eb + 2048 + lane * 16);
        float ss = d4(e0) + d4(e1) + d4(e2);
        #pragma unroll
        for (int m = 1; m < 64; m <<= 1) ss += __shfl_xor(ss, m, 64);

        if (!isCent) {
            const float sc = 1.0f / fmaxf(sqrtf(ss), 1e-8f);
            unsigned int* op = en8 + (size_t)row * (EMB / 4) + lane;
            op[0] = pk8(e0, sc); op[64] = pk8(e1, sc); op[128] = pk8(e2, sc);

            const uint8_t* lb = &lds[buf][4 * EMB_B + w * LOG_B];
            float4 l0 = *(const float4*)(lb + lane * 16);
            float4 l1 = *(const float4*)(lb + 1024 + lane * 16);
            float4 l2 = *(const float4*)(lb + 2048 + lane * 16);
            float es = e4(l0) + e4(l1) + e4(l2);
            if (lane < 58) {
                float4 l3 = *(const float4*)(lb + 3072 + lane * 16);
                es += e4(l3);
            }
            #pragma unroll
            for (int m = 1; m < 64; m <<= 1) es += __shfl_xor(es, m, 64);
            if (lane == 0) {
                const int t = targets[row];
                const float xt = *(const float*)(lb + t * 4);   // from LDS
                ce_row[row] = __logf(es) - xt;
            }
        } else {
            const float sc = (row < NCLS) ? (1.0f / fmaxf(sqrtf(ss), 1e-8f)) : 0.0f;
            unsigned int* op = cn8 + (size_t)row * (EMB / 4) + lane;
            op[0] = pk8(e0, sc); op[64] = pk8(e1, sc); op[128] = pk8(e2, sc);
        }
        __syncthreads();   // drains next group's DMA + guards buffer reuse
        buf ^= 1;
    }
#undef PSTAGE
}

// ---- GEMM + online stats. 512 blocks = 2/CU (cross-block drain hiding).
// BM=128 x BN=256, BK=64, 4 waves (2x2), per-wave 64x128 (acc[4][8]).
// global_load_lds staging, dbuf, 0-conflict XOR swizzle (r8-verified).
// Transposed MFMA: D[class][emb] -> per-row softmax reduce = 2 shfls. ----
__global__ __launch_bounds__(256, 2) void gemm_kernel(
    const uint8_t* __restrict__ en8, const uint8_t* __restrict__ cn8,
    const int* __restrict__ targets,
    float* __restrict__ partZ, float* __restrict__ partS2,
    float* __restrict__ et_out)
{
    __shared__ __align__(128) uint8_t lds[2][BUFB];

    const int bid  = blockIdx.x;
    const int tid  = threadIdx.x;
    const int lane = tid & 63;
    const int warp = tid >> 6;

    // XCD-grouped decode: XCD g = bid&7 owns mbs [16g, 16g+16).
    const int g   = bid & 7;
    const int s   = bid >> 3;          // 0..63
    const int mb  = g * 16 + (s >> 2);
    const int nb  = s & 3;
    const int R0  = mb * BM;
    const int Nc0 = nb * BN;
    const int wr  = warp >> 1;         // 0,1: 64-row emb half
    const int wc  = warp & 1;          // 0,1: 128-class half
    const int l15 = lane & 15;
    const int rq  = lane >> 4;

    // Staging: thread covers chunk ci = j*256 + tid; LDS row = j*64+(tid>>2),
    // chunk c = tid&3; source col pre-swizzled (rule #21).
    const int csw  = ((tid & 3) * 16) ^ (((tid >> 3) & 3) << 4);
    const int srow = tid >> 2;
    size_t asrc[2], bsrc[4];
    #pragma unroll
    for (int j = 0; j < 2; ++j) asrc[j] = (size_t)(R0  + j * 64 + srow) * EMB + csw;
    #pragma unroll
    for (int j = 0; j < 4; ++j) bsrc[j] = (size_t)(Nc0 + j * 64 + srow) * EMB + csw;
    const uint8_t* enb = en8;
    const uint8_t* cnb = cn8;

#define STAGE(b, kt) do { const size_t ko = (size_t)(kt) * 64;               \
    _Pragma("unroll") for (int j = 0; j < 2; ++j)                            \
        GLOAD16(enb + asrc[j] + ko, &lds[b][j * 4096 + tid * 16]);           \
    _Pragma("unroll") for (int j = 0; j < 4; ++j)                            \
        GLOAD16(cnb + bsrc[j] + ko, &lds[b][ABYTES + j * 4096 + tid * 16]);  \
} while (0)

    // Fragment read offsets (b128 = kk0|kk1 pair), same XOR family.
    const int cx   = (rq * 16) ^ (((l15 >> 1) & 3) << 4);
    const int aoff = (wr * 64 + l15) * 64 + cx;              // + m*1024
    const int boff = ABYTES + (wc * 128 + l15) * 64 + cx;    // + n*1024

    f32x4 acc[4][8];
    #pragma unroll
    for (int m = 0; m < 4; ++m)
        #pragma unroll
        for (int n = 0; n < 8; ++n) acc[m][n] = (f32x4){0.f, 0.f, 0.f, 0.f};

    STAGE(0, 0);
    __syncthreads();

    for (int kt = 0; kt < KT; ++kt) {
        const int buf = kt & 1;
        if (kt + 1 < KT) STAGE(buf ^ 1, kt + 1);
        const uint8_t* L = &lds[buf][0];
        v2i64 af[4], bf[8];
        #pragma unroll
        for (int m = 0; m < 4; ++m) af[m] = *(const v2i64*)(L + aoff + m * 1024);
        #pragma unroll
        for (int n = 0; n < 8; ++n) bf[n] = *(const v2i64*)(L + boff + n * 1024);
        #pragma unroll
        for (int kk = 0; kk < 2; ++kk)
            #pragma unroll
            for (int m = 0; m < 4; ++m)
                #pragma unroll
                for (int n = 0; n < 8; ++n)
                    acc[m][n] = __builtin_amdgcn_mfma_f32_16x16x32_fp8_fp8(
                        bf[n][kk], af[m][kk], acc[m][n], 0, 0, 0);
        __syncthreads();   // drains next-tile DMA + guards overwrite
    }
#undef STAGE

    // ---- epilogue: acc[m][n][r] = sim[class = Nc0+wc*128+n*16+rq*4+r]
    //                                 [emb row = R0+wr*64+m*16+l15]
    const int plane = nb * 2 + wc;    // 128-class slab, 0..7
    #pragma unroll
    for (int m = 0; m < 4; ++m) {
        const int row = R0 + wr * 64 + m * 16 + l15;
        const int t   = targets[row];
        float z = 0.f, s2 = 0.f;
        #pragma unroll
        for (int n = 0; n < 8; ++n) {
            const int cb = Nc0 + wc * 128 + n * 16 + rq * 4;
            #pragma unroll
            for (int r = 0; r < 4; ++r) {
                const bool valid = (cb + r) < NCLS;
                float e = valid ? __expf(acc[m][n][r]) : 0.f;
                z += e; s2 += e * e;
                if (cb + r == t) et_out[row] = e;   // unique owner grid-wide
            }
        }
        z  += __shfl_xor(z, 16, 64);  z  += __shfl_xor(z, 32, 64);
        s2 += __shfl_xor(s2, 16, 64); s2 += __shfl_xor(s2, 32, 64);
        if (rq == 0) {
            partZ [(size_t)plane * BATCH + row] = z;
            partS2[(size_t)plane * BATCH + row] = s2;
        }
    }
}

// ---- finalize stage 1: per-row loss terms -> 64 block partials ----
__global__ __launch_bounds__(256) void finalize1(
    const float* __restrict__ partZ, const float* __restrict__ partS2,
    const float* __restrict__ et_out, const float* __restrict__ ce_row,
    const float* __restrict__ u, float* __restrict__ fpart)
{
    __shared__ float red[4];
    const int row  = blockIdx.x * 256 + threadIdx.x;
    const int lane = threadIdx.x & 63;
    float z = 0.f, s2 = 0.f;
    #pragma unroll
    for (int i = 0; i < 8; ++i) {
        z  += partZ [(size_t)i * BATCH + row];
        s2 += partS2[(size_t)i * BATCH + row];
    }
    float et = et_out[row];
    float invz = 1.0f / z;
    float pt = et * invz;
    float c = (s2 * invz * invz - 2.0f * pt + 1.0f) * (1.0f / ((float)BATCH * (float)NCLS))
            + (1.0f - pt) * u[0] * (1.0f / (float)BATCH)
            + ce_row[row] * (1.0f / (float)BATCH);
    #pragma unroll
    for (int m = 1; m < 64; m <<= 1) c += __shfl_xor(c, m, 64);
    if (lane == 0) red[threadIdx.x >> 6] = c;
    __syncthreads();
    if (threadIdx.x == 0) fpart[blockIdx.x] = red[0] + red[1] + red[2] + red[3];
}

// ---- finalize stage 2: 64 partials -> scalar (plain store, no atomics) ----
__global__ __launch_bounds__(64) void finalize2(
    const float* __restrict__ fpart, float* __restrict__ out)
{
    const int lane = threadIdx.x;
    float s = fpart[lane];
    #pragma unroll
    for (int m = 1; m < 64; m <<= 1) s += __shfl_xor(s, m, 64);
    if (lane == 0) out[0] = s;
}

extern "C" void kernel_launch(void* const* d_in, const int* in_sizes, int n_in,
                              void* d_out, int out_size, void* d_ws, size_t ws_size,
                              hipStream_t stream) {
    const float* emb       = (const float*)d_in[0];
    const float* logits    = (const float*)d_in[1];
    const int*   targets   = (const int*)d_in[2];
    const float* centroids = (const float*)d_in[3];
    const float* u         = (const float*)d_in[4];
    float* out = (float*)d_out;

    uint8_t* en8  = (uint8_t*)d_ws;                         // 16384*768 = 12,582,912
    uint8_t* cn8  = en8 + (size_t)BATCH * EMB;              //  1024*768 =    786,432
    float* partZ  = (float*)(cn8 + (size_t)NPAD * EMB);     //  8*16384*4 =   524,288
    float* partS2 = partZ + 8 * BATCH;                      //               524,288
    float* et_out = partS2 + 8 * BATCH;                     //                65,536
    float* ce_row = et_out + BATCH;                         //                65,536
    float* fpart  = ce_row + BATCH;                         //                   256

    prep_row<<<PREP_BATCH_BLKS + PREP_CENT_BLKS, 256, 0, stream>>>(
        emb, centroids, logits, targets,
        (unsigned int*)en8, (unsigned int*)cn8, ce_row);
    gemm_kernel<<<GEMM_BLKS, 256, 0, stream>>>(en8, cn8, targets, partZ, partS2, et_out);
    finalize1<<<BATCH / 256, 256, 0, stream>>>(partZ, partS2, et_out, ce_row, u, fpart);
    finalize2<<<1, 64, 0, stream>>>(fpart, out);
}

// Round 15
// 49.502 us; speedup vs baseline: 1.1319x; 1.1319x over previous
//
#include <hip/hip_runtime.h>
#include <hip/hip_bf16.h>
#include <stdint.h>

#define BATCH 16384
#define NCLS 1000
#define NPAD 1024        // 8 N-blocks x 128
#define EMB 768
#define KT 12            // K-steps of 64
#define BM 128
#define BN 128
#define ABYTES 8192      // 128 rows x 64 B
#define BUFB 16384       // A 8K + B 8K
#define GEMM_BLKS 1024   // 128 mb x 8 nb
#define CE_BLKS 4096     // BATCH/4, wave per row

typedef __attribute__((ext_vector_type(4))) float f32x4;
typedef long v2i64 __attribute__((ext_vector_type(2)));

#define GLOAD16(g, l) __builtin_amdgcn_global_load_lds(              \
    (const __attribute__((address_space(1))) unsigned int*)(g),       \
    (__attribute__((address_space(3))) unsigned int*)(l), 16, 0, 0)

__device__ __forceinline__ float d4(float4 v) {
    return v.x*v.x + v.y*v.y + v.z*v.z + v.w*v.w;
}
__device__ __forceinline__ float e4(float4 v) {
    return __expf(v.x) + __expf(v.y) + __expf(v.z) + __expf(v.w);
}
__device__ __forceinline__ unsigned int pk8(float4 v, float s) {
    int p = 0;
    p = __builtin_amdgcn_cvt_pk_fp8_f32(v.x * s, v.y * s, p, false);
    p = __builtin_amdgcn_cvt_pk_fp8_f32(v.z * s, v.w * s, p, true);
    return (unsigned int)p;
}

// ---- prep_ec: emb+cent normalize ONLY (CE moved to overlap with gemm).
// Block-per-row (r12 best shape), 192 threads = exactly 1 float4/thread.
// Blocks 0..16383: emb rows. Blocks 16384..17407: cent rows (pads -> 0). ----
__global__ __launch_bounds__(192) void prep_ec(
    const float* __restrict__ emb, const float* __restrict__ cent,
    unsigned int* __restrict__ en8, unsigned int* __restrict__ cn8)
{
    __shared__ float ssp[3];
    const int b    = blockIdx.x;
    const int tid  = threadIdx.x;
    const int w    = tid >> 6;
    const int lane = tid & 63;

    const bool isC = b >= BATCH;
    const int row  = isC ? b - BATCH : b;
    const bool valid = !isC || row < NCLS;

    const float4* src = isC ? (const float4*)(cent + (size_t)row * EMB)
                            : (const float4*)(emb + (size_t)row * EMB);
    float4 v = (valid) ? src[tid] : make_float4(0.f, 0.f, 0.f, 0.f);

    float ss = d4(v);
    #pragma unroll
    for (int m = 1; m < 64; m <<= 1) ss += __shfl_xor(ss, m, 64);
    if (lane == 0) ssp[w] = ss;
    __syncthreads();
    const float tot = ssp[0] + ssp[1] + ssp[2];
    const float sc = valid ? (1.0f / fmaxf(sqrtf(tot), 1e-8f)) : 0.0f;

    unsigned int* op = (isC ? cn8 : en8) + (size_t)row * (EMB / 4);
    op[tid] = pk8(v, sc);
}

// ---- gemm_ce: bids < 1024 -> GEMM tiles; bids 1024..5119 -> CE rows.
// GEMM: BM=128 x BN=128, BK=64, 32KB LDS (small so CE blocks co-reside:
// ~4 gemm + 1 CE per CU early, 5 CE/CU after gemm drains). 4 waves 2x2,
// per-wave 64x64 (acc[4][4]). global_load_lds dbuf staging, 0-conflict
// XOR swizzle (r8-verified). Transposed MFMA: D[class][emb].
// CE is HBM-bound, GEMM is L2/MFMA-bound -> overlap hides CE's 65 MB. ----
__global__ __launch_bounds__(256) void gemm_ce(
    const uint8_t* __restrict__ en8, const uint8_t* __restrict__ cn8,
    const float* __restrict__ logits, const int* __restrict__ targets,
    float* __restrict__ partZ, float* __restrict__ partS2,
    float* __restrict__ et_out, float* __restrict__ ce_row)
{
    __shared__ __align__(128) uint8_t lds[2][BUFB];

    const int bid  = blockIdx.x;
    const int tid  = threadIdx.x;
    const int lane = tid & 63;
    const int warp = tid >> 6;

    if (bid >= GEMM_BLKS) {
        // ---------------- CE: ce_row[row] = lse(logits_row) - x_t ----------
        const int row = (bid - GEMM_BLKS) * 4 + warp;
        const float* rp = logits + (size_t)row * NCLS;
        const float4* r4 = (const float4*)rp;
        float4 v0 = r4[lane];
        float4 v1 = r4[lane + 64];
        float4 v2 = r4[lane + 128];
        const bool has = lane < 58;
        float4 v3 = has ? r4[lane + 192] : v0;
        float s = e4(v0) + e4(v1) + e4(v2);
        if (has) s += e4(v3);
        #pragma unroll
        for (int m = 1; m < 64; m <<= 1) s += __shfl_xor(s, m, 64);
        if (lane == 0) {
            float xt = rp[targets[row]];
            ce_row[row] = __logf(s) - xt;
        }
        return;
    }

    // ---------------- GEMM path ----------------
    // XCD-grouped decode: XCD g = bid&7 owns mbs [16g, 16g+16), all 8 nb.
    const int g   = bid & 7;
    const int s   = bid >> 3;          // 0..127
    const int mb  = g * 16 + (s >> 3);
    const int nb  = s & 7;
    const int R0  = mb * BM;
    const int Nc0 = nb * BN;
    const int wr  = warp >> 1;         // 0,1: 64-row emb half
    const int wc  = warp & 1;          // 0,1: 64-class half
    const int l15 = lane & 15;
    const int rq  = lane >> 4;

    // Staging: thread covers chunk ci = j*256 + tid; LDS row = j*64+(tid>>2),
    // chunk c = tid&3; source col pre-swizzled (rule #21).
    const int csw  = ((tid & 3) * 16) ^ (((tid >> 3) & 3) << 4);
    const int srow = tid >> 2;
    size_t asrc[2], bsrc[2];
    #pragma unroll
    for (int j = 0; j < 2; ++j) {
        asrc[j] = (size_t)(R0  + j * 64 + srow) * EMB + csw;
        bsrc[j] = (size_t)(Nc0 + j * 64 + srow) * EMB + csw;
    }
    const uint8_t* enb = en8;
    const uint8_t* cnb = cn8;

#define STAGE(b, kt) do { const size_t ko = (size_t)(kt) * 64;               \
    _Pragma("unroll") for (int j = 0; j < 2; ++j)                            \
        GLOAD16(enb + asrc[j] + ko, &lds[b][j * 4096 + tid * 16]);           \
    _Pragma("unroll") for (int j = 0; j < 2; ++j)                            \
        GLOAD16(cnb + bsrc[j] + ko, &lds[b][ABYTES + j * 4096 + tid * 16]);  \
} while (0)

    // Fragment read offsets (b128 = kk0|kk1 pair), same XOR family.
    const int cx   = (rq * 16) ^ (((l15 >> 1) & 3) << 4);
    const int aoff = (wr * 64 + l15) * 64 + cx;             // + m*1024
    const int boff = ABYTES + (wc * 64 + l15) * 64 + cx;    // + n*1024

    f32x4 acc[4][4];
    #pragma unroll
    for (int m = 0; m < 4; ++m)
        #pragma unroll
        for (int n = 0; n < 4; ++n) acc[m][n] = (f32x4){0.f, 0.f, 0.f, 0.f};

    STAGE(0, 0);
    __syncthreads();

    for (int kt = 0; kt < KT; ++kt) {
        const int buf = kt & 1;
        if (kt + 1 < KT) STAGE(buf ^ 1, kt + 1);
        const uint8_t* L = &lds[buf][0];
        v2i64 af[4], bf[4];
        #pragma unroll
        for (int m = 0; m < 4; ++m) af[m] = *(const v2i64*)(L + aoff + m * 1024);
        #pragma unroll
        for (int n = 0; n < 4; ++n) bf[n] = *(const v2i64*)(L + boff + n * 1024);
        #pragma unroll
        for (int kk = 0; kk < 2; ++kk)
            #pragma unroll
            for (int m = 0; m < 4; ++m)
                #pragma unroll
                for (int n = 0; n < 4; ++n)
                    acc[m][n] = __builtin_amdgcn_mfma_f32_16x16x32_fp8_fp8(
                        bf[n][kk], af[m][kk], acc[m][n], 0, 0, 0);
        __syncthreads();   // drains next-tile DMA + guards overwrite
    }
#undef STAGE

    // ---- epilogue: acc[m][n][r] = sim[class = Nc0+wc*64+n*16+rq*4+r]
    //                                 [emb row = R0+wr*64+m*16+l15]
    const int plane = nb * 2 + wc;    // 64-class slab, 0..15
    #pragma unroll
    for (int m = 0; m < 4; ++m) {
        const int row = R0 + wr * 64 + m * 16 + l15;
        const int t   = targets[row];
        float z = 0.f, s2 = 0.f;
        #pragma unroll
        for (int n = 0; n < 4; ++n) {
            const int cb = Nc0 + wc * 64 + n * 16 + rq * 4;
            #pragma unroll
            for (int r = 0; r < 4; ++r) {
                const bool valid = (cb + r) < NCLS;
                float e = valid ? __expf(acc[m][n][r]) : 0.f;
                z += e; s2 += e * e;
                if (cb + r == t) et_out[row] = e;   // unique owner grid-wide
            }
        }
        z  += __shfl_xor(z, 16, 64);  z  += __shfl_xor(z, 32, 64);
        s2 += __shfl_xor(s2, 16, 64); s2 += __shfl_xor(s2, 32, 64);
        if (rq == 0) {
            partZ [(size_t)plane * BATCH + row] = z;
            partS2[(size_t)plane * BATCH + row] = s2;
        }
    }
}

// ---- finalize stage 1: per-row loss terms -> 64 block partials ----
__global__ __launch_bounds__(256) void finalize1(
    const float* __restrict__ partZ, const float* __restrict__ partS2,
    const float* __restrict__ et_out, const float* __restrict__ ce_row,
    const float* __restrict__ u, float* __restrict__ fpart)
{
    __shared__ float red[4];
    const int row  = blockIdx.x * 256 + threadIdx.x;
    const int lane = threadIdx.x & 63;
    float z = 0.f, s2 = 0.f;
    #pragma unroll
    for (int i = 0; i < 16; ++i) {
        z  += partZ [(size_t)i * BATCH + row];
        s2 += partS2[(size_t)i * BATCH + row];
    }
    float et = et_out[row];
    float invz = 1.0f / z;
    float pt = et * invz;
    float c = (s2 * invz * invz - 2.0f * pt + 1.0f) * (1.0f / ((float)BATCH * (float)NCLS))
            + (1.0f - pt) * u[0] * (1.0f / (float)BATCH)
            + ce_row[row] * (1.0f / (float)BATCH);
    #pragma unroll
    for (int m = 1; m < 64; m <<= 1) c += __shfl_xor(c, m, 64);
    if (lane == 0) red[threadIdx.x >> 6] = c;
    __syncthreads();
    if (threadIdx.x == 0) fpart[blockIdx.x] = red[0] + red[1] + red[2] + red[3];
}

// ---- finalize stage 2: 64 partials -> scalar (plain store, no atomics) ----
__global__ __launch_bounds__(64) void finalize2(
    const float* __restrict__ fpart, float* __restrict__ out)
{
    const int lane = threadIdx.x;
    float s = fpart[lane];
    #pragma unroll
    for (int m = 1; m < 64; m <<= 1) s += __shfl_xor(s, m, 64);
    if (lane == 0) out[0] = s;
}

extern "C" void kernel_launch(void* const* d_in, const int* in_sizes, int n_in,
                              void* d_out, int out_size, void* d_ws, size_t ws_size,
                              hipStream_t stream) {
    const float* emb       = (const float*)d_in[0];
    const float* logits    = (const float*)d_in[1];
    const int*   targets   = (const int*)d_in[2];
    const float* centroids = (const float*)d_in[3];
    const float* u         = (const float*)d_in[4];
    float* out = (float*)d_out;

    uint8_t* en8  = (uint8_t*)d_ws;                         // 16384*768 = 12,582,912
    uint8_t* cn8  = en8 + (size_t)BATCH * EMB;              //  1024*768 =    786,432
    float* partZ  = (float*)(cn8 + (size_t)NPAD * EMB);     // 16*16384*4 = 1,048,576
    float* partS2 = partZ + 16 * BATCH;                     //             1,048,576
    float* et_out = partS2 + 16 * BATCH;                    //                65,536
    float* ce_row = et_out + BATCH;                         //                65,536
    float* fpart  = ce_row + BATCH;                         //                   256

    prep_ec<<<BATCH + NPAD, 192, 0, stream>>>(emb, centroids,
                                              (unsigned int*)en8, (unsigned int*)cn8);
    gemm_ce<<<GEMM_BLKS + CE_BLKS, 256, 0, stream>>>(en8, cn8, logits, targets,
                                                     partZ, partS2, et_out, ce_row);
    finalize1<<<BATCH / 256, 256, 0, stream>>>(partZ, partS2, et_out, ce_row, u, fpart);
    finalize2<<<1, 64, 0, stream>>>(fpart, out);
}